// Round 5
// baseline (288.811 us; speedup 1.0000x reference)
//
#include <hip/hip_runtime.h>

// -------------------- helpers --------------------
static __device__ __forceinline__ float4 ld4(const float* p) { return *(const float4*)p; }
static __device__ __forceinline__ float b2f(unsigned short u) {
    return __uint_as_float((unsigned)u << 16);
}
static __device__ __forceinline__ float b2f_lo(unsigned u) { return __uint_as_float(u << 16); }
static __device__ __forceinline__ float b2f_hi(unsigned u) { return __uint_as_float(u & 0xFFFF0000u); }
static __device__ __forceinline__ unsigned short f2b(float f) {   // round-to-nearest-even
    unsigned x = __float_as_uint(f);
    return (unsigned short)((x + 0x7FFFu + ((x >> 16) & 1u)) >> 16);
}
static __device__ __forceinline__ unsigned pk2(float lo, float hi) {
    return (unsigned)f2b(lo) | ((unsigned)f2b(hi) << 16);
}

typedef __attribute__((ext_vector_type(8))) short bf16x8;   // 8 bf16 (4 VGPRs)
typedef __attribute__((ext_vector_type(4))) float f32x4;    // MFMA accumulator

#define NPB 256              // nodes per bin (pow2: ld = d & 255, bin = d >> 8)
#define CAPE 5120            // per-bin edge capacity (mean 4092, sigma 64 -> 16 sigma slack)

// math: out[d] = dinv[d]*( g[d] + sum_e ew_e * g[src_e] ) + bias,  g = dinv (.) h
// CSR stores (src, raw ew); dinv folded into gemm2 epilogue and csr_build's h-scale pass.

// MFMA GEMM scheme (both layers): 64-row x 64-col tile per block, 4 waves.
// A (x rows) and B (W^T) staged in LDS as bf16 hi/lo pairs, padded row stride
// (136 or 72 ushorts) -> only 2-way bank aliasing (free). Fragments:
//   A/B: row/col = lane&15, k = (lane>>4)*8 + j  (ds_read_b128 per frag)
//   C/D: col = lane&15, row = (lane>>4)*4 + reg
// Split precision: fp32 x ~= x_hi + x_lo (bf16 each); h = xh*Wh + xl*Wh + xh*Wl.

// ==================== fused kernel 1: gemm1 (x@W1 -> h) + edge binning ====================
// blocks [0, gb): MFMA gemm tile. blocks [gb, gb+bb): bin 4096 edges by dst>>8.
// packed entry: [ew:32][ld:8][src:17]
__global__ __launch_bounds__(256) void k_fused1(const float* __restrict__ A,
                                                const float* __restrict__ W0,
                                                unsigned short* __restrict__ gout,
                                                const int* __restrict__ src,
                                                const int* __restrict__ dst,
                                                const float* __restrict__ ew,
                                                int* __restrict__ bin_cnt,
                                                unsigned long long* __restrict__ ebuf,
                                                int n, int E, int gb, int NB) {
    __shared__ unsigned short xh[64 * 136];    // 17408 B
    __shared__ unsigned short xl[64 * 136];
    __shared__ unsigned short Wth[64 * 136];   // W^T: [col][k], K=128
    __shared__ unsigned short Wtl[64 * 136];
    __shared__ int hist[512];
    __shared__ int hbase[512];
    int tid = threadIdx.x;

    if ((int)blockIdx.x < gb) {
        int row0 = blockIdx.x * 64;
        // ---- stage W^T hi/lo (8192 elems; W L2-hot across blocks) ----
        for (int j = tid; j < 2048; j += 256) {
            int c = j >> 5, kq = (j & 31) * 4;
            ushort4 uh, ul;
            #pragma unroll
            for (int i = 0; i < 4; i++) {
                float wv = W0[(size_t)(kq + i) * 64 + c];
                unsigned short hi = f2b(wv);
                unsigned short lo = f2b(wv - b2f(hi));
                ((unsigned short*)&uh)[i] = hi;
                ((unsigned short*)&ul)[i] = lo;
            }
            *(ushort4*)&Wth[c * 136 + kq] = uh;
            *(ushort4*)&Wtl[c * 136 + kq] = ul;
        }
        // ---- stage x rows -> hi/lo bf16 ----
        for (int j = tid; j < 2048; j += 256) {
            int r = j >> 5, kc = (j & 31) * 4;
            int grow = row0 + r;
            float4 v = make_float4(0.f, 0.f, 0.f, 0.f);
            if (grow < n) v = ld4(A + (size_t)grow * 128 + kc);
            ushort4 uh, ul;
            uh.x = f2b(v.x); ul.x = f2b(v.x - b2f(uh.x));
            uh.y = f2b(v.y); ul.y = f2b(v.y - b2f(uh.y));
            uh.z = f2b(v.z); ul.z = f2b(v.z - b2f(uh.z));
            uh.w = f2b(v.w); ul.w = f2b(v.w - b2f(uh.w));
            *(ushort4*)&xh[r * 136 + kc] = uh;
            *(ushort4*)&xl[r * 136 + kc] = ul;
        }
        __syncthreads();
        // ---- MFMA: wave w owns rows w*16..w*16+15 ----
        int w = tid >> 6, lane = tid & 63;
        int rA = lane & 15;
        int g8 = (lane >> 4) * 8;
        f32x4 acc[4] = {{0.f, 0.f, 0.f, 0.f}, {0.f, 0.f, 0.f, 0.f},
                        {0.f, 0.f, 0.f, 0.f}, {0.f, 0.f, 0.f, 0.f}};
        #pragma unroll
        for (int kb = 0; kb < 4; kb++) {
            bf16x8 ah = *(const bf16x8*)&xh[(w * 16 + rA) * 136 + kb * 32 + g8];
            bf16x8 al = *(const bf16x8*)&xl[(w * 16 + rA) * 136 + kb * 32 + g8];
            #pragma unroll
            for (int ct = 0; ct < 4; ct++) {
                bf16x8 bh = *(const bf16x8*)&Wth[(ct * 16 + rA) * 136 + kb * 32 + g8];
                bf16x8 bl = *(const bf16x8*)&Wtl[(ct * 16 + rA) * 136 + kb * 32 + g8];
                acc[ct] = __builtin_amdgcn_mfma_f32_16x16x32_bf16(ah, bh, acc[ct], 0, 0, 0);
                acc[ct] = __builtin_amdgcn_mfma_f32_16x16x32_bf16(al, bh, acc[ct], 0, 0, 0);
                acc[ct] = __builtin_amdgcn_mfma_f32_16x16x32_bf16(ah, bl, acc[ct], 0, 0, 0);
            }
        }
        // ---- epilogue: D row = w*16 + (lane>>4)*4 + reg, col = ct*16 + (lane&15) ----
        int rbase = row0 + w * 16 + (lane >> 4) * 4;
        #pragma unroll
        for (int reg = 0; reg < 4; reg++) {
            int grow = rbase + reg;
            if (grow < n) {
                #pragma unroll
                for (int ct = 0; ct < 4; ct++)
                    gout[(size_t)grow * 64 + ct * 16 + rA] = f2b(acc[ct][reg]);
            }
        }
    } else {
        // ---------------- bin path: 4096 edges
        for (int j = tid; j < NB; j += 256) hist[j] = 0;
        __syncthreads();
        int e0 = ((int)blockIdx.x - gb) * 4096;
        unsigned long long pk[16]; int bb[16]; int loc[16];
        #pragma unroll
        for (int j = 0; j < 16; j++) {
            int e = e0 + j * 256 + tid;
            if (e < E) {
                int s = src[e];
                int d = dst[e];
                float w = ew[e];
                bb[j] = d >> 8;
                pk[j] = ((unsigned long long)__float_as_uint(w) << 32) |
                        (unsigned)((d & (NPB - 1)) << 17) | (unsigned)s;
                loc[j] = atomicAdd(&hist[bb[j]], 1);
            } else bb[j] = -1;
        }
        __syncthreads();
        for (int j = tid; j < NB; j += 256) hbase[j] = atomicAdd(&bin_cnt[j], hist[j]);
        __syncthreads();
        #pragma unroll
        for (int j = 0; j < 16; j++) {
            if (bb[j] >= 0)
                ebuf[(size_t)bb[j] * CAPE + hbase[bb[j]] + loc[j]] = pk[j];
        }
    }
}

// ==================== pass 2: per-bin LDS-resident count+scan+scatter + h-scale ============
__global__ __launch_bounds__(512) void k_csr_build(const unsigned long long* __restrict__ ebuf,
                                                   const int* __restrict__ bin_cnt,
                                                   int2* __restrict__ rowcnt,
                                                   float* __restrict__ dinv,
                                                   unsigned long long* __restrict__ csr,
                                                   unsigned short* __restrict__ h0,
                                                   int n) {
    __shared__ unsigned long long eL[CAPE];   // 40 KB
    __shared__ unsigned cntL[NPB];
    __shared__ unsigned ewsL[NPB];
    __shared__ unsigned fillL[NPB];
    __shared__ int scanL[512];
    __shared__ int rowL[NPB];
    __shared__ float dinvL[NPB];
    __shared__ int binbase_s;
    int b = blockIdx.x;
    int tid = threadIdx.x;
    if (tid < NPB) { cntL[tid] = 0; ewsL[tid] = 0; fillL[tid] = 0; }
    scanL[tid] = (tid < b) ? bin_cnt[tid] : 0;
    __syncthreads();
    int m = bin_cnt[b];
    const unsigned long long* eb = ebuf + (size_t)b * CAPE;
    for (int i = tid; i < m; i += 512) {
        unsigned long long pk = eb[i];
        eL[i] = pk;
        int ld = (int)((pk >> 17) & (NPB - 1));
        float w = __uint_as_float((unsigned)(pk >> 32));
        atomicAdd(&cntL[ld], 1u);
        atomicAdd(&ewsL[ld], (unsigned)(w * 16777216.0f));   // 2^24 fixed point
    }
    __syncthreads();
    // bin base = sum of bin_cnt[0..b)
    #pragma unroll
    for (int off = 256; off > 0; off >>= 1) {
        if (tid < off) scanL[tid] += scanL[tid + off];
        __syncthreads();
    }
    if (tid == 0) binbase_s = scanL[0];
    __syncthreads();
    // exclusive prefix over cntL (512-wide, entries >= NPB are zero)
    int v = (tid < NPB) ? (int)cntL[tid] : 0;
    scanL[tid] = v;
    __syncthreads();
    #pragma unroll
    for (int off = 1; off < 512; off <<= 1) {
        int t = (tid >= off) ? scanL[tid - off] : 0;
        __syncthreads();
        scanL[tid] += t;
        __syncthreads();
    }
    if (tid < NPB) {
        int rp = binbase_s + scanL[tid] - v;
        rowL[tid] = rp;
        float dv = rsqrtf(1.0f + (float)ewsL[tid] * (1.0f / 16777216.0f));
        dinvL[tid] = dv;
        int node = b * NPB + tid;
        if (node < n) {
            rowcnt[node] = make_int2(rp, v);
            dinv[node] = dv;
        }
    }
    __syncthreads();
    // scatter from LDS; csr entry = (src, raw ew)
    for (int i = tid; i < m; i += 512) {
        unsigned long long pk = eL[i];
        int s = (int)(pk & 0x1FFFF);
        int ld = (int)((pk >> 17) & (NPB - 1));
        int pos = rowL[ld] + (int)atomicAdd(&fillL[ld], 1u);
        csr[pos] = (unsigned long long)(unsigned)s | (pk & 0xFFFFFFFF00000000ull);
    }
    // fused h-scale: g = dinv (.) h for this block's 256 nodes
    for (int idx = tid; idx < NPB * 8; idx += 512) {
        int ln = idx >> 3;
        int node = b * NPB + ln;
        if (node < n) {
            float sc = dinvL[ln];
            unsigned short* hp = h0 + (size_t)node * 64 + (idx & 7) * 8;
            uint4 u = *(uint4*)hp;
            u.x = pk2(b2f_lo(u.x) * sc, b2f_hi(u.x) * sc);
            u.y = pk2(b2f_lo(u.y) * sc, b2f_hi(u.y) * sc);
            u.z = pk2(b2f_lo(u.z) * sc, b2f_hi(u.z) * sc);
            u.w = pk2(b2f_lo(u.w) * sc, b2f_hi(u.w) * sc);
            *(uint4*)hp = u;
        }
    }
}

// ==================== layer-2 GEMM (MFMA): g2 = dinv (.) (h @ [Wmu|Wlv]) ====================
// A = h rows (bf16, exact); B = W^T hi/lo (cols 0-31 Wmu, 32-63 Wlv); K=64.
__global__ __launch_bounds__(256) void k_gemm2(const unsigned short* __restrict__ h,
                                               const float* __restrict__ Wmu,
                                               const float* __restrict__ Wlv,
                                               const float* __restrict__ dinv,
                                               unsigned short* __restrict__ out, int n) {
    __shared__ unsigned short hA[64 * 72];     // 9216 B
    __shared__ unsigned short Wth[64 * 72];
    __shared__ unsigned short Wtl[64 * 72];
    int tid = threadIdx.x;
    int row0 = blockIdx.x * 64;
    // stage W^T hi/lo (4096 elems)
    for (int j = tid; j < 1024; j += 256) {
        int c = j >> 4, kq = (j & 15) * 4;
        const float* Wsrc = (c < 32) ? Wmu : Wlv;
        int cc = c & 31;
        ushort4 uh, ul;
        #pragma unroll
        for (int i = 0; i < 4; i++) {
            float wv = Wsrc[(size_t)(kq + i) * 32 + cc];
            unsigned short hi = f2b(wv);
            unsigned short lo = f2b(wv - b2f(hi));
            ((unsigned short*)&uh)[i] = hi;
            ((unsigned short*)&ul)[i] = lo;
        }
        *(ushort4*)&Wth[c * 72 + kq] = uh;
        *(ushort4*)&Wtl[c * 72 + kq] = ul;
    }
    // stage h rows (bf16 passthrough)
    for (int j = tid; j < 512; j += 256) {
        int r = j >> 3, q = (j & 7) * 8;
        int grow = row0 + r;
        uint4 u = make_uint4(0u, 0u, 0u, 0u);
        if (grow < n) u = *(const uint4*)(h + (size_t)grow * 64 + q);
        *(uint4*)&hA[r * 72 + q] = u;
    }
    __syncthreads();
    int w = tid >> 6, lane = tid & 63;
    int rA = lane & 15;
    int g8 = (lane >> 4) * 8;
    f32x4 acc[4] = {{0.f, 0.f, 0.f, 0.f}, {0.f, 0.f, 0.f, 0.f},
                    {0.f, 0.f, 0.f, 0.f}, {0.f, 0.f, 0.f, 0.f}};
    #pragma unroll
    for (int kb = 0; kb < 2; kb++) {
        bf16x8 a = *(const bf16x8*)&hA[(w * 16 + rA) * 72 + kb * 32 + g8];
        #pragma unroll
        for (int ct = 0; ct < 4; ct++) {
            bf16x8 bh = *(const bf16x8*)&Wth[(ct * 16 + rA) * 72 + kb * 32 + g8];
            bf16x8 bl = *(const bf16x8*)&Wtl[(ct * 16 + rA) * 72 + kb * 32 + g8];
            acc[ct] = __builtin_amdgcn_mfma_f32_16x16x32_bf16(a, bh, acc[ct], 0, 0, 0);
            acc[ct] = __builtin_amdgcn_mfma_f32_16x16x32_bf16(a, bl, acc[ct], 0, 0, 0);
        }
    }
    int rbase = row0 + w * 16 + (lane >> 4) * 4;
    #pragma unroll
    for (int reg = 0; reg < 4; reg++) {
        int grow = rbase + reg;
        if (grow < n) {
            float sc = dinv[grow];
            #pragma unroll
            for (int ct = 0; ct < 4; ct++)
                out[(size_t)grow * 64 + ct * 16 + rA] = f2b(acc[ct][reg] * sc);
        }
    }
}

// -------------------- propagation: one wave per node, 8 edges per VMEM instruction ----------
static __device__ __forceinline__ void acc8(float* a, uint4 r, float wt) {
    a[0] = fmaf(b2f_lo(r.x), wt, a[0]); a[1] = fmaf(b2f_hi(r.x), wt, a[1]);
    a[2] = fmaf(b2f_lo(r.y), wt, a[2]); a[3] = fmaf(b2f_hi(r.y), wt, a[3]);
    a[4] = fmaf(b2f_lo(r.z), wt, a[4]); a[5] = fmaf(b2f_hi(r.z), wt, a[5]);
    a[6] = fmaf(b2f_lo(r.w), wt, a[6]); a[7] = fmaf(b2f_hi(r.w), wt, a[7]);
}

template<bool RELU, bool SPLIT_OUT>
__global__ __launch_bounds__(256) void k_prop(const unsigned short* __restrict__ g,
                                              const int2* __restrict__ csr,
                                              const int2* __restrict__ rowcnt,
                                              const float* __restrict__ dinv,
                                              const float* __restrict__ bias0,
                                              const float* __restrict__ bias1,
                                              void* __restrict__ outv, int n) {
    int node = blockIdx.x * 4 + (threadIdx.x >> 6);
    if (node >= n) return;
    int lane = threadIdx.x & 63;
    int q = lane >> 3;          // edge slot 0..7
    int t = lane & 7;           // channel octet: channels 8t..8t+7
    uint4 sr = *(const uint4*)(g + (size_t)node * 64 + t * 8);
    int2 rc = rowcnt[node];
    const int2* ep = csr + rc.x;
    int m = rc.y;
    float a[8] = {};
    for (int e = 0; e < m; e += 32) {
        int e1 = e + q, e2 = e1 + 8, e3 = e1 + 16, e4 = e1 + 24;
        int i1 = min(e1, m - 1), i2 = min(e2, m - 1);
        int i3 = min(e3, m - 1), i4 = min(e4, m - 1);
        int2 p1 = ep[i1];
        int2 p2 = ep[i2];
        int2 p3 = ep[i3];
        int2 p4 = ep[i4];
        uint4 r1 = *(const uint4*)(g + (size_t)p1.x * 64 + t * 8);
        uint4 r2 = *(const uint4*)(g + (size_t)p2.x * 64 + t * 8);
        uint4 r3 = *(const uint4*)(g + (size_t)p3.x * 64 + t * 8);
        uint4 r4 = *(const uint4*)(g + (size_t)p4.x * 64 + t * 8);
        float w1 = (e1 < m) ? __int_as_float(p1.y) : 0.f;
        float w2 = (e2 < m) ? __int_as_float(p2.y) : 0.f;
        float w3 = (e3 < m) ? __int_as_float(p3.y) : 0.f;
        float w4 = (e4 < m) ? __int_as_float(p4.y) : 0.f;
        acc8(a, r1, w1);
        acc8(a, r2, w2);
        acc8(a, r3, w3);
        acc8(a, r4, w4);
    }
    #pragma unroll
    for (int i = 0; i < 8; i++) {
        a[i] += __shfl_xor(a[i], 8);
        a[i] += __shfl_xor(a[i], 16);
        a[i] += __shfl_xor(a[i], 32);
    }
    if (q != 0) return;
    a[0] += b2f_lo(sr.x); a[1] += b2f_hi(sr.x);
    a[2] += b2f_lo(sr.y); a[3] += b2f_hi(sr.y);
    a[4] += b2f_lo(sr.z); a[5] += b2f_hi(sr.z);
    a[6] += b2f_lo(sr.w); a[7] += b2f_hi(sr.w);
    float di = dinv[node];
    #pragma unroll
    for (int i = 0; i < 8; i++) a[i] *= di;
    if (!SPLIT_OUT) {
        float4 b0 = ld4(bias0 + t * 8);
        float4 b1 = ld4(bias0 + t * 8 + 4);
        a[0] += b0.x; a[1] += b0.y; a[2] += b0.z; a[3] += b0.w;
        a[4] += b1.x; a[5] += b1.y; a[6] += b1.z; a[7] += b1.w;
        if (RELU) {
            #pragma unroll
            for (int i = 0; i < 8; i++) a[i] = fmaxf(a[i], 0.f);
        }
        uint4 u = make_uint4(pk2(a[0], a[1]), pk2(a[2], a[3]),
                             pk2(a[4], a[5]), pk2(a[6], a[7]));
        *(uint4*)((unsigned short*)outv + (size_t)node * 64 + t * 8) = u;
    } else {
        float* out = (float*)outv;
        const float* bp = (t < 4) ? (bias0 + t * 8) : (bias1 + (t - 4) * 8);
        size_t base = (t < 4) ? ((size_t)node * 32 + t * 8)
                              : ((size_t)n * 32 + (size_t)node * 32 + (t - 4) * 8);
        float4 b0 = ld4(bp);
        float4 b1 = ld4(bp + 4);
        float4 v0 = make_float4(a[0] + b0.x, a[1] + b0.y, a[2] + b0.z, a[3] + b0.w);
        float4 v1 = make_float4(a[4] + b1.x, a[5] + b1.y, a[6] + b1.z, a[7] + b1.w);
        *(float4*)&out[base] = v0;
        *(float4*)&out[base + 4] = v1;
    }
}

// -------------------- launch --------------------
extern "C" void kernel_launch(void* const* d_in, const int* in_sizes, int n_in,
                              void* d_out, int out_size, void* d_ws, size_t ws_size,
                              hipStream_t stream) {
    const float* x   = (const float*)d_in[0];
    const int*   ei  = (const int*)d_in[1];   // [2, E]
    const float* ew  = (const float*)d_in[2];
    const float* W1  = (const float*)d_in[3];
    const float* b1  = (const float*)d_in[4];
    const float* Wmu = (const float*)d_in[5];
    const float* bmu = (const float*)d_in[6];
    const float* Wlv = (const float*)d_in[7];
    const float* blv = (const float*)d_in[8];
    float* outp = (float*)d_out;

    const int n = in_sizes[0] / 128;
    const int E = in_sizes[2];
    const int* src = ei;
    const int* dst = ei + E;
    const int NB = (n + NPB - 1) / NPB;            // bins of 256 nodes (391)

    // workspace layout
    size_t o = 0;
    auto alloc = [&](size_t bytes) { void* p = (char*)d_ws + o; o += (bytes + 511) & ~(size_t)511; return p; };
    int*   bin_cnt  = (int*)alloc((size_t)NB * 4);                 // memset 0
    int2*  rowcnt   = (int2*)alloc((size_t)n * 8);
    float* dinv     = (float*)alloc((size_t)n * 4);
    unsigned long long* csr  = (unsigned long long*)alloc((size_t)E * 8);
    unsigned long long* ebuf = (unsigned long long*)alloc((size_t)NB * CAPE * 8);
    unsigned short* g0 = (unsigned short*)alloc((size_t)n * 64 * 2);   // bf16
    unsigned short* h  = (unsigned short*)alloc((size_t)n * 64 * 2);   // bf16
    unsigned short* g2 = g0;   // gemm2 output reuses g0 (dead after prop1)

    const int gb = (n + 63) / 64;                  // gemm blocks (1563), 64-row MFMA tiles
    const int bb = (E + 4095) / 4096;              // bin blocks (391)

    hipMemsetAsync(bin_cnt, 0, (size_t)NB * 4, stream);
    k_fused1<<<gb + bb, 256, 0, stream>>>(x, W1, g0, src, dst, ew,
                                          bin_cnt, ebuf, n, E, gb, NB);
    k_csr_build<<<NB, 512, 0, stream>>>(ebuf, bin_cnt, rowcnt, dinv, csr, g0, n);
    k_prop<true, false><<<(n + 3) / 4, 256, 0, stream>>>(g0, (const int2*)csr, rowcnt, dinv,
                                                         b1, nullptr, h, n);
    k_gemm2<<<gb, 256, 0, stream>>>(h, Wmu, Wlv, dinv, g2, n);
    k_prop<false, true><<<(n + 3) / 4, 256, 0, stream>>>(g2, (const int2*)csr, rowcnt, dinv,
                                                         bmu, blv, outp, n);
}

// Round 6
// 278.263 us; speedup vs baseline: 1.0379x; 1.0379x over previous
//
#include <hip/hip_runtime.h>

// -------------------- helpers --------------------
static __device__ __forceinline__ float4 ld4(const float* p) { return *(const float4*)p; }
static __device__ __forceinline__ float b2f(unsigned short u) {
    return __uint_as_float((unsigned)u << 16);
}
static __device__ __forceinline__ float b2f_lo(unsigned u) { return __uint_as_float(u << 16); }
static __device__ __forceinline__ float b2f_hi(unsigned u) { return __uint_as_float(u & 0xFFFF0000u); }
static __device__ __forceinline__ unsigned short f2b(float f) {   // round-to-nearest-even
    unsigned x = __float_as_uint(f);
    return (unsigned short)((x + 0x7FFFu + ((x >> 16) & 1u)) >> 16);
}
static __device__ __forceinline__ unsigned pk2(float lo, float hi) {
    return (unsigned)f2b(lo) | ((unsigned)f2b(hi) << 16);
}

typedef __attribute__((ext_vector_type(8))) short bf16x8;   // 8 bf16 (4 VGPRs)
typedef __attribute__((ext_vector_type(4))) float f32x4;    // MFMA accumulator

#define NPB 256              // nodes per bin (pow2: ld = d & 255, bin = d >> 8)
#define CAPE 5120            // per-bin edge capacity (mean 4092, sigma 64 -> 16 sigma slack)

// math: out[d] = dinv[d]*( g[d] + sum_e ew_e * g[src_e] ) + bias,  g = dinv (.) h
// CSR stores (src, raw ew); dinv folded into gemm2 epilogue and csr_build's h-scale pass.

// MFMA fragment mapping (verified on HW in R5, absmax unchanged):
//   A: row = lane&15, k = (lane>>4)*8 + j      B: col = lane&15, k = (lane>>4)*8 + j
//   C/D: col = lane&15, row = (lane>>4)*4 + reg
// W is pre-split (hi/lo bf16) and pre-laid-out per-lane by k_prep:
//   Wf[frag * 512 + lane * 8 + j], frag = kb*8 + ct*2 + s   (s: 0=hi 1=lo)
// Split precision: fp32 x ~= xh + xl (trunc split); h = xh*Wh + xl*Wh + xh*Wl.

// ==================== prep: W -> per-lane hi/lo fragments (runs once) ====================
__global__ __launch_bounds__(256) void k_prep(const float* __restrict__ W1,
                                              const float* __restrict__ Wmu,
                                              const float* __restrict__ Wlv,
                                              unsigned short* __restrict__ Wf1,
                                              unsigned short* __restrict__ Wf2) {
    int tid = threadIdx.x;
    if (blockIdx.x == 0) {
        // layer-1: K=128, 64 cols -> 32 frags (kb<4, ct<4, s<2)
        for (int idx = tid; idx < 2048; idx += 256) {
            int frag = idx >> 6, lane = idx & 63;
            int s = frag & 1, ct = (frag >> 1) & 3, kb = frag >> 3;
            int rA = lane & 15, g8 = (lane >> 4) * 8;
            int c = ct * 16 + rA;
            unsigned short* dstp = Wf1 + frag * 512 + lane * 8;
            for (int j = 0; j < 8; j++) {
                float wv = W1[(size_t)(kb * 32 + g8 + j) * 64 + c];
                unsigned short hi = f2b(wv);
                dstp[j] = (s == 0) ? hi : f2b(wv - b2f(hi));
            }
        }
    } else {
        // layer-2: K=64, cols 0-31 = Wmu, 32-63 = Wlv -> 16 frags (kb<2)
        for (int idx = tid; idx < 1024; idx += 256) {
            int frag = idx >> 6, lane = idx & 63;
            int s = frag & 1, ct = (frag >> 1) & 3, kb = frag >> 3;
            int rA = lane & 15, g8 = (lane >> 4) * 8;
            int c = ct * 16 + rA;
            int k0 = kb * 32 + g8;
            unsigned short* dstp = Wf2 + frag * 512 + lane * 8;
            for (int j = 0; j < 8; j++) {
                float wv = (c < 32) ? Wmu[(size_t)(k0 + j) * 32 + c]
                                    : Wlv[(size_t)(k0 + j) * 32 + (c - 32)];
                unsigned short hi = f2b(wv);
                dstp[j] = (s == 0) ? hi : f2b(wv - b2f(hi));
            }
        }
    }
}

// truncation split: x = hi + lo (bf16 each), residual error ~2^-16 relative
static __device__ __forceinline__ void split8(const float* xv, bf16x8& ah, bf16x8& al) {
    #pragma unroll
    for (int j = 0; j < 8; j++) {
        unsigned u = __float_as_uint(xv[j]);
        float res = xv[j] - __uint_as_float(u & 0xFFFF0000u);
        ah[j] = (short)(u >> 16);
        al[j] = (short)(__float_as_uint(res) >> 16);
    }
}

// ==================== fused kernel 1: gemm1 (x@W1 -> h) + edge binning ====================
// blocks [0, gb): register-direct MFMA, 64 rows/block, 4 waves, no LDS, no barriers.
// blocks [gb, gb+bb): bin 4096 edges by dst>>8 into ebuf segments (packed u64).
// packed entry: [ew:32][ld:8][src:17]
__global__ __launch_bounds__(256) void k_fused1(const float* __restrict__ A,
                                                const unsigned short* __restrict__ Wf1,
                                                unsigned short* __restrict__ gout,
                                                const int* __restrict__ src,
                                                const int* __restrict__ dst,
                                                const float* __restrict__ ew,
                                                int* __restrict__ bin_cnt,
                                                unsigned long long* __restrict__ ebuf,
                                                int n, int E, int gb, int NB) {
    __shared__ int hist[512];
    __shared__ int hbase[512];
    int tid = threadIdx.x;

    if ((int)blockIdx.x < gb) {
        int row0 = blockIdx.x * 64;
        int w = tid >> 6, lane = tid & 63;
        int rA = lane & 15, g8 = (lane >> 4) * 8;
        int row = row0 + w * 16 + rA;
        const float* xr = A + (size_t)min(row, n - 1) * 128;
        f32x4 acc[4] = {{0.f, 0.f, 0.f, 0.f}, {0.f, 0.f, 0.f, 0.f},
                        {0.f, 0.f, 0.f, 0.f}, {0.f, 0.f, 0.f, 0.f}};
        #pragma unroll
        for (int kb = 0; kb < 4; kb++) {
            float4 v0 = ld4(xr + kb * 32 + g8);
            float4 v1 = ld4(xr + kb * 32 + g8 + 4);
            float xv[8] = {v0.x, v0.y, v0.z, v0.w, v1.x, v1.y, v1.z, v1.w};
            bf16x8 ah, al;
            split8(xv, ah, al);
            const unsigned short* wb = Wf1 + (size_t)(kb * 8) * 512 + lane * 8;
            #pragma unroll
            for (int ct = 0; ct < 4; ct++) {
                bf16x8 bh = *(const bf16x8*)(wb + (ct * 2 + 0) * 512);
                bf16x8 bl = *(const bf16x8*)(wb + (ct * 2 + 1) * 512);
                acc[ct] = __builtin_amdgcn_mfma_f32_16x16x32_bf16(ah, bh, acc[ct], 0, 0, 0);
                acc[ct] = __builtin_amdgcn_mfma_f32_16x16x32_bf16(al, bh, acc[ct], 0, 0, 0);
                acc[ct] = __builtin_amdgcn_mfma_f32_16x16x32_bf16(ah, bl, acc[ct], 0, 0, 0);
            }
        }
        int rbase = row0 + w * 16 + (lane >> 4) * 4;
        #pragma unroll
        for (int reg = 0; reg < 4; reg++) {
            int grow = rbase + reg;
            if (grow < n) {
                #pragma unroll
                for (int ct = 0; ct < 4; ct++)
                    gout[(size_t)grow * 64 + ct * 16 + rA] = f2b(acc[ct][reg]);
            }
        }
    } else {
        // ---------------- bin path: 4096 edges
        for (int j = tid; j < NB; j += 256) hist[j] = 0;
        __syncthreads();
        int e0 = ((int)blockIdx.x - gb) * 4096;
        unsigned long long pk[16]; int bb[16]; int loc[16];
        #pragma unroll
        for (int j = 0; j < 16; j++) {
            int e = e0 + j * 256 + tid;
            if (e < E) {
                int s = src[e];
                int d = dst[e];
                float w = ew[e];
                bb[j] = d >> 8;
                pk[j] = ((unsigned long long)__float_as_uint(w) << 32) |
                        (unsigned)((d & (NPB - 1)) << 17) | (unsigned)s;
                loc[j] = atomicAdd(&hist[bb[j]], 1);
            } else bb[j] = -1;
        }
        __syncthreads();
        for (int j = tid; j < NB; j += 256) hbase[j] = atomicAdd(&bin_cnt[j], hist[j]);
        __syncthreads();
        #pragma unroll
        for (int j = 0; j < 16; j++) {
            if (bb[j] >= 0)
                ebuf[(size_t)bb[j] * CAPE + hbase[bb[j]] + loc[j]] = pk[j];
        }
    }
}

// ==================== pass 2: per-bin LDS-resident count+scan+scatter + h-scale ============
__global__ __launch_bounds__(512) void k_csr_build(const unsigned long long* __restrict__ ebuf,
                                                   const int* __restrict__ bin_cnt,
                                                   int2* __restrict__ rowcnt,
                                                   float* __restrict__ dinv,
                                                   unsigned long long* __restrict__ csr,
                                                   unsigned short* __restrict__ h0,
                                                   int n) {
    __shared__ unsigned long long eL[CAPE];   // 40 KB
    __shared__ unsigned cntL[NPB];
    __shared__ unsigned ewsL[NPB];
    __shared__ unsigned fillL[NPB];
    __shared__ int scanL[512];
    __shared__ int rowL[NPB];
    __shared__ float dinvL[NPB];
    __shared__ int binbase_s;
    int b = blockIdx.x;
    int tid = threadIdx.x;
    if (tid < NPB) { cntL[tid] = 0; ewsL[tid] = 0; fillL[tid] = 0; }
    scanL[tid] = (tid < b) ? bin_cnt[tid] : 0;
    __syncthreads();
    int m = bin_cnt[b];
    const unsigned long long* eb = ebuf + (size_t)b * CAPE;
    for (int i = tid; i < m; i += 512) {
        unsigned long long pk = eb[i];
        eL[i] = pk;
        int ld = (int)((pk >> 17) & (NPB - 1));
        float w = __uint_as_float((unsigned)(pk >> 32));
        atomicAdd(&cntL[ld], 1u);
        atomicAdd(&ewsL[ld], (unsigned)(w * 16777216.0f));   // 2^24 fixed point
    }
    __syncthreads();
    // bin base = sum of bin_cnt[0..b)
    #pragma unroll
    for (int off = 256; off > 0; off >>= 1) {
        if (tid < off) scanL[tid] += scanL[tid + off];
        __syncthreads();
    }
    if (tid == 0) binbase_s = scanL[0];
    __syncthreads();
    // exclusive prefix over cntL (512-wide, entries >= NPB are zero)
    int v = (tid < NPB) ? (int)cntL[tid] : 0;
    scanL[tid] = v;
    __syncthreads();
    #pragma unroll
    for (int off = 1; off < 512; off <<= 1) {
        int t = (tid >= off) ? scanL[tid - off] : 0;
        __syncthreads();
        scanL[tid] += t;
        __syncthreads();
    }
    if (tid < NPB) {
        int rp = binbase_s + scanL[tid] - v;
        rowL[tid] = rp;
        float dv = rsqrtf(1.0f + (float)ewsL[tid] * (1.0f / 16777216.0f));
        dinvL[tid] = dv;
        int node = b * NPB + tid;
        if (node < n) {
            rowcnt[node] = make_int2(rp, v);
            dinv[node] = dv;
        }
    }
    __syncthreads();
    // scatter from LDS; csr entry = (src, raw ew)
    for (int i = tid; i < m; i += 512) {
        unsigned long long pk = eL[i];
        int s = (int)(pk & 0x1FFFF);
        int ld = (int)((pk >> 17) & (NPB - 1));
        int pos = rowL[ld] + (int)atomicAdd(&fillL[ld], 1u);
        csr[pos] = (unsigned long long)(unsigned)s | (pk & 0xFFFFFFFF00000000ull);
    }
    // fused h-scale: g = dinv (.) h for this block's 256 nodes
    for (int idx = tid; idx < NPB * 8; idx += 512) {
        int ln = idx >> 3;
        int node = b * NPB + ln;
        if (node < n) {
            float sc = dinvL[ln];
            unsigned short* hp = h0 + (size_t)node * 64 + (idx & 7) * 8;
            uint4 u = *(uint4*)hp;
            u.x = pk2(b2f_lo(u.x) * sc, b2f_hi(u.x) * sc);
            u.y = pk2(b2f_lo(u.y) * sc, b2f_hi(u.y) * sc);
            u.z = pk2(b2f_lo(u.z) * sc, b2f_hi(u.z) * sc);
            u.w = pk2(b2f_lo(u.w) * sc, b2f_hi(u.w) * sc);
            *(uint4*)hp = u;
        }
    }
}

// ==================== layer-2 GEMM (register-direct MFMA): g2 = dinv (.) (h @ [Wmu|Wlv]) ====
__global__ __launch_bounds__(256) void k_gemm2(const unsigned short* __restrict__ h,
                                               const unsigned short* __restrict__ Wf2,
                                               const float* __restrict__ dinv,
                                               unsigned short* __restrict__ out, int n) {
    int tid = threadIdx.x;
    int row0 = blockIdx.x * 64;
    int w = tid >> 6, lane = tid & 63;
    int rA = lane & 15, g8 = (lane >> 4) * 8;
    int row = row0 + w * 16 + rA;
    const unsigned short* hr = h + (size_t)min(row, n - 1) * 64;
    f32x4 acc[4] = {{0.f, 0.f, 0.f, 0.f}, {0.f, 0.f, 0.f, 0.f},
                    {0.f, 0.f, 0.f, 0.f}, {0.f, 0.f, 0.f, 0.f}};
    #pragma unroll
    for (int kb = 0; kb < 2; kb++) {
        bf16x8 a = *(const bf16x8*)(hr + kb * 32 + g8);
        const unsigned short* wb = Wf2 + (size_t)(kb * 8) * 512 + lane * 8;
        #pragma unroll
        for (int ct = 0; ct < 4; ct++) {
            bf16x8 bh = *(const bf16x8*)(wb + (ct * 2 + 0) * 512);
            bf16x8 bl = *(const bf16x8*)(wb + (ct * 2 + 1) * 512);
            acc[ct] = __builtin_amdgcn_mfma_f32_16x16x32_bf16(a, bh, acc[ct], 0, 0, 0);
            acc[ct] = __builtin_amdgcn_mfma_f32_16x16x32_bf16(a, bl, acc[ct], 0, 0, 0);
        }
    }
    int rbase = row0 + w * 16 + (lane >> 4) * 4;
    #pragma unroll
    for (int reg = 0; reg < 4; reg++) {
        int grow = rbase + reg;
        if (grow < n) {
            float sc = dinv[grow];
            #pragma unroll
            for (int ct = 0; ct < 4; ct++)
                out[(size_t)grow * 64 + ct * 16 + rA] = f2b(acc[ct][reg] * sc);
        }
    }
}

// -------------------- propagation: one wave per node, 8 edges per VMEM instruction ----------
static __device__ __forceinline__ void acc8(float* a, uint4 r, float wt) {
    a[0] = fmaf(b2f_lo(r.x), wt, a[0]); a[1] = fmaf(b2f_hi(r.x), wt, a[1]);
    a[2] = fmaf(b2f_lo(r.y), wt, a[2]); a[3] = fmaf(b2f_hi(r.y), wt, a[3]);
    a[4] = fmaf(b2f_lo(r.z), wt, a[4]); a[5] = fmaf(b2f_hi(r.z), wt, a[5]);
    a[6] = fmaf(b2f_lo(r.w), wt, a[6]); a[7] = fmaf(b2f_hi(r.w), wt, a[7]);
}

template<bool RELU, bool SPLIT_OUT>
__global__ __launch_bounds__(256) void k_prop(const unsigned short* __restrict__ g,
                                              const int2* __restrict__ csr,
                                              const int2* __restrict__ rowcnt,
                                              const float* __restrict__ dinv,
                                              const float* __restrict__ bias0,
                                              const float* __restrict__ bias1,
                                              void* __restrict__ outv, int n) {
    int node = blockIdx.x * 4 + (threadIdx.x >> 6);
    if (node >= n) return;
    int lane = threadIdx.x & 63;
    int q = lane >> 3;          // edge slot 0..7
    int t = lane & 7;           // channel octet: channels 8t..8t+7
    uint4 sr = *(const uint4*)(g + (size_t)node * 64 + t * 8);
    int2 rc = rowcnt[node];
    const int2* ep = csr + rc.x;
    int m = rc.y;
    float a[8] = {};
    for (int e = 0; e < m; e += 32) {
        int e1 = e + q, e2 = e1 + 8, e3 = e1 + 16, e4 = e1 + 24;
        int i1 = min(e1, m - 1), i2 = min(e2, m - 1);
        int i3 = min(e3, m - 1), i4 = min(e4, m - 1);
        int2 p1 = ep[i1];
        int2 p2 = ep[i2];
        int2 p3 = ep[i3];
        int2 p4 = ep[i4];
        uint4 r1 = *(const uint4*)(g + (size_t)p1.x * 64 + t * 8);
        uint4 r2 = *(const uint4*)(g + (size_t)p2.x * 64 + t * 8);
        uint4 r3 = *(const uint4*)(g + (size_t)p3.x * 64 + t * 8);
        uint4 r4 = *(const uint4*)(g + (size_t)p4.x * 64 + t * 8);
        float w1 = (e1 < m) ? __int_as_float(p1.y) : 0.f;
        float w2 = (e2 < m) ? __int_as_float(p2.y) : 0.f;
        float w3 = (e3 < m) ? __int_as_float(p3.y) : 0.f;
        float w4 = (e4 < m) ? __int_as_float(p4.y) : 0.f;
        acc8(a, r1, w1);
        acc8(a, r2, w2);
        acc8(a, r3, w3);
        acc8(a, r4, w4);
    }
    #pragma unroll
    for (int i = 0; i < 8; i++) {
        a[i] += __shfl_xor(a[i], 8);
        a[i] += __shfl_xor(a[i], 16);
        a[i] += __shfl_xor(a[i], 32);
    }
    if (q != 0) return;
    a[0] += b2f_lo(sr.x); a[1] += b2f_hi(sr.x);
    a[2] += b2f_lo(sr.y); a[3] += b2f_hi(sr.y);
    a[4] += b2f_lo(sr.z); a[5] += b2f_hi(sr.z);
    a[6] += b2f_lo(sr.w); a[7] += b2f_hi(sr.w);
    float di = dinv[node];
    #pragma unroll
    for (int i = 0; i < 8; i++) a[i] *= di;
    if (!SPLIT_OUT) {
        float4 b0 = ld4(bias0 + t * 8);
        float4 b1 = ld4(bias0 + t * 8 + 4);
        a[0] += b0.x; a[1] += b0.y; a[2] += b0.z; a[3] += b0.w;
        a[4] += b1.x; a[5] += b1.y; a[6] += b1.z; a[7] += b1.w;
        if (RELU) {
            #pragma unroll
            for (int i = 0; i < 8; i++) a[i] = fmaxf(a[i], 0.f);
        }
        uint4 u = make_uint4(pk2(a[0], a[1]), pk2(a[2], a[3]),
                             pk2(a[4], a[5]), pk2(a[6], a[7]));
        *(uint4*)((unsigned short*)outv + (size_t)node * 64 + t * 8) = u;
    } else {
        float* out = (float*)outv;
        const float* bp = (t < 4) ? (bias0 + t * 8) : (bias1 + (t - 4) * 8);
        size_t base = (t < 4) ? ((size_t)node * 32 + t * 8)
                              : ((size_t)n * 32 + (size_t)node * 32 + (t - 4) * 8);
        float4 b0 = ld4(bp);
        float4 b1 = ld4(bp + 4);
        float4 v0 = make_float4(a[0] + b0.x, a[1] + b0.y, a[2] + b0.z, a[3] + b0.w);
        float4 v1 = make_float4(a[4] + b1.x, a[5] + b1.y, a[6] + b1.z, a[7] + b1.w);
        *(float4*)&out[base] = v0;
        *(float4*)&out[base + 4] = v1;
    }
}

// -------------------- launch --------------------
extern "C" void kernel_launch(void* const* d_in, const int* in_sizes, int n_in,
                              void* d_out, int out_size, void* d_ws, size_t ws_size,
                              hipStream_t stream) {
    const float* x   = (const float*)d_in[0];
    const int*   ei  = (const int*)d_in[1];   // [2, E]
    const float* ew  = (const float*)d_in[2];
    const float* W1  = (const float*)d_in[3];
    const float* b1  = (const float*)d_in[4];
    const float* Wmu = (const float*)d_in[5];
    const float* bmu = (const float*)d_in[6];
    const float* Wlv = (const float*)d_in[7];
    const float* blv = (const float*)d_in[8];
    float* outp = (float*)d_out;

    const int n = in_sizes[0] / 128;
    const int E = in_sizes[2];
    const int* src = ei;
    const int* dst = ei + E;
    const int NB = (n + NPB - 1) / NPB;            // bins of 256 nodes (391)

    // workspace layout
    size_t o = 0;
    auto alloc = [&](size_t bytes) { void* p = (char*)d_ws + o; o += (bytes + 511) & ~(size_t)511; return p; };
    int*   bin_cnt  = (int*)alloc((size_t)NB * 4);                 // memset 0
    int2*  rowcnt   = (int2*)alloc((size_t)n * 8);
    float* dinv     = (float*)alloc((size_t)n * 4);
    unsigned long long* csr  = (unsigned long long*)alloc((size_t)E * 8);
    unsigned long long* ebuf = (unsigned long long*)alloc((size_t)NB * CAPE * 8);
    unsigned short* g0 = (unsigned short*)alloc((size_t)n * 64 * 2);   // bf16
    unsigned short* h  = (unsigned short*)alloc((size_t)n * 64 * 2);   // bf16
    unsigned short* Wf1 = (unsigned short*)alloc(32 * 512 * 2);        // 32 KB
    unsigned short* Wf2 = (unsigned short*)alloc(16 * 512 * 2);        // 16 KB
    unsigned short* g2 = g0;   // gemm2 output reuses g0 (dead after prop1)

    const int gb = (n + 63) / 64;                  // gemm blocks (1563), 64-row tiles
    const int bb = (E + 4095) / 4096;              // bin blocks (391)

    k_prep<<<2, 256, 0, stream>>>(W1, Wmu, Wlv, Wf1, Wf2);
    hipMemsetAsync(bin_cnt, 0, (size_t)NB * 4, stream);
    k_fused1<<<gb + bb, 256, 0, stream>>>(x, Wf1, g0, src, dst, ew,
                                          bin_cnt, ebuf, n, E, gb, NB);
    k_csr_build<<<NB, 512, 0, stream>>>(ebuf, bin_cnt, rowcnt, dinv, csr, g0, n);
    k_prop<true, false><<<(n + 3) / 4, 256, 0, stream>>>(g0, (const int2*)csr, rowcnt, dinv,
                                                         b1, nullptr, h, n);
    k_gemm2<<<gb, 256, 0, stream>>>(h, Wf2, dinv, g2, n);
    k_prop<false, true><<<(n + 3) / 4, 256, 0, stream>>>(g2, (const int2*)csr, rowcnt, dinv,
                                                         bmu, blv, outp, n);
}

// Round 7
// 272.992 us; speedup vs baseline: 1.0579x; 1.0193x over previous
//
#include <hip/hip_runtime.h>

// -------------------- helpers --------------------
static __device__ __forceinline__ float4 ld4(const float* p) { return *(const float4*)p; }
static __device__ __forceinline__ float b2f(unsigned short u) {
    return __uint_as_float((unsigned)u << 16);
}
static __device__ __forceinline__ float b2f_lo(unsigned u) { return __uint_as_float(u << 16); }
static __device__ __forceinline__ float b2f_hi(unsigned u) { return __uint_as_float(u & 0xFFFF0000u); }
static __device__ __forceinline__ unsigned short f2b(float f) {   // round-to-nearest-even
    unsigned x = __float_as_uint(f);
    return (unsigned short)((x + 0x7FFFu + ((x >> 16) & 1u)) >> 16);
}
static __device__ __forceinline__ unsigned pk2(float lo, float hi) {
    return (unsigned)f2b(lo) | ((unsigned)f2b(hi) << 16);
}

typedef __attribute__((ext_vector_type(8))) short bf16x8;   // 8 bf16 (4 VGPRs)
typedef __attribute__((ext_vector_type(4))) float f32x4;    // MFMA accumulator

#define NPB 256              // nodes per bin (pow2: ld = d & 255, bin = d >> 8)
#define CAPE 5120            // per-bin edge capacity (mean 4092, sigma 64 -> 16 sigma slack)

// math: out[d] = dinv[d]*( dinv[d]*h[d] + sum_e ew_e*dinv[src_e]*h[src_e] ) + bias  (layer 1)
//       out[d] = dinv[d]*( g2[d] + sum_e ew_e*g2[src_e] ) + bias, g2 = dinv (.) (h@W) (layer 2)
// CSR stores (src, raw ew). Layer-1 dinv[src] applied inside prop (DSCALE) — no h-scale pass.

// MFMA fragment mapping (HW-verified R5/R6):
//   A: row = lane&15, k = (lane>>4)*8 + j      B: col = lane&15, k = (lane>>4)*8 + j
//   C/D: col = lane&15, row = (lane>>4)*4 + reg
// W pre-split (hi/lo bf16) per-lane by k_prep: Wf[frag*512 + lane*8 + j], frag = kb*8+ct*2+s.

// ==================== prep: W -> per-lane hi/lo fragments (runs once) ====================
__global__ __launch_bounds__(256) void k_prep(const float* __restrict__ W1,
                                              const float* __restrict__ Wmu,
                                              const float* __restrict__ Wlv,
                                              unsigned short* __restrict__ Wf1,
                                              unsigned short* __restrict__ Wf2) {
    int tid = threadIdx.x;
    if (blockIdx.x == 0) {
        // layer-1: K=128, 64 cols -> 32 frags (kb<4, ct<4, s<2)
        for (int idx = tid; idx < 2048; idx += 256) {
            int frag = idx >> 6, lane = idx & 63;
            int s = frag & 1, ct = (frag >> 1) & 3, kb = frag >> 3;
            int rA = lane & 15, g8 = (lane >> 4) * 8;
            int c = ct * 16 + rA;
            unsigned short* dstp = Wf1 + frag * 512 + lane * 8;
            for (int j = 0; j < 8; j++) {
                float wv = W1[(size_t)(kb * 32 + g8 + j) * 64 + c];
                unsigned short hi = f2b(wv);
                dstp[j] = (s == 0) ? hi : f2b(wv - b2f(hi));
            }
        }
    } else {
        // layer-2: K=64, cols 0-31 = Wmu, 32-63 = Wlv -> 16 frags (kb<2)
        for (int idx = tid; idx < 1024; idx += 256) {
            int frag = idx >> 6, lane = idx & 63;
            int s = frag & 1, ct = (frag >> 1) & 3, kb = frag >> 3;
            int rA = lane & 15, g8 = (lane >> 4) * 8;
            int c = ct * 16 + rA;
            int k0 = kb * 32 + g8;
            unsigned short* dstp = Wf2 + frag * 512 + lane * 8;
            for (int j = 0; j < 8; j++) {
                float wv = (c < 32) ? Wmu[(size_t)(k0 + j) * 32 + c]
                                    : Wlv[(size_t)(k0 + j) * 32 + (c - 32)];
                unsigned short hi = f2b(wv);
                dstp[j] = (s == 0) ? hi : f2b(wv - b2f(hi));
            }
        }
    }
}

// truncation split: x = hi + lo (bf16 each), residual error ~2^-16 relative
static __device__ __forceinline__ void split8(const float* xv, bf16x8& ah, bf16x8& al) {
    #pragma unroll
    for (int j = 0; j < 8; j++) {
        unsigned u = __float_as_uint(xv[j]);
        float res = xv[j] - __uint_as_float(u & 0xFFFF0000u);
        ah[j] = (short)(u >> 16);
        al[j] = (short)(__float_as_uint(res) >> 16);
    }
}

// ==================== fused kernel 1: edge binning + gemm1 (x@W1 -> h) ====================
// blocks [0, bb): bin 4096 edges (launched FIRST — they are the long pole, no gemm dep).
// blocks [bb, bb+gb): register-direct MFMA, 128 rows/block (2 row-tiles/wave), no LDS/barriers.
__global__ __launch_bounds__(256) void k_fused1(const float* __restrict__ A,
                                                const unsigned short* __restrict__ Wf1,
                                                unsigned short* __restrict__ gout,
                                                const int* __restrict__ src,
                                                const int* __restrict__ dst,
                                                const float* __restrict__ ew,
                                                int* __restrict__ bin_cnt,
                                                unsigned long long* __restrict__ ebuf,
                                                int n, int E, int bb_cnt, int NB) {
    __shared__ int hist[512];
    __shared__ int hbase[512];
    int tid = threadIdx.x;

    if ((int)blockIdx.x >= bb_cnt) {
        int row0 = ((int)blockIdx.x - bb_cnt) * 128;
        int w = tid >> 6, lane = tid & 63;
        int rA = lane & 15, g8 = (lane >> 4) * 8;
        int rowa = row0 + w * 16 + rA;
        int rowb = rowa + 64;
        const float* xa = A + (size_t)min(rowa, n - 1) * 128;
        const float* xb = A + (size_t)min(rowb, n - 1) * 128;
        f32x4 acc0[4] = {{0.f,0.f,0.f,0.f},{0.f,0.f,0.f,0.f},{0.f,0.f,0.f,0.f},{0.f,0.f,0.f,0.f}};
        f32x4 acc1[4] = {{0.f,0.f,0.f,0.f},{0.f,0.f,0.f,0.f},{0.f,0.f,0.f,0.f},{0.f,0.f,0.f,0.f}};
        #pragma unroll
        for (int kb = 0; kb < 4; kb++) {
            float4 va0 = ld4(xa + kb * 32 + g8);
            float4 va1 = ld4(xa + kb * 32 + g8 + 4);
            float4 vb0 = ld4(xb + kb * 32 + g8);
            float4 vb1 = ld4(xb + kb * 32 + g8 + 4);
            float xva[8] = {va0.x, va0.y, va0.z, va0.w, va1.x, va1.y, va1.z, va1.w};
            float xvb[8] = {vb0.x, vb0.y, vb0.z, vb0.w, vb1.x, vb1.y, vb1.z, vb1.w};
            bf16x8 ahA, alA, ahB, alB;
            split8(xva, ahA, alA);
            split8(xvb, ahB, alB);
            const unsigned short* wb = Wf1 + (size_t)(kb * 8) * 512 + lane * 8;
            #pragma unroll
            for (int ct = 0; ct < 4; ct++) {
                bf16x8 bh = *(const bf16x8*)(wb + (ct * 2 + 0) * 512);
                bf16x8 bl = *(const bf16x8*)(wb + (ct * 2 + 1) * 512);
                acc0[ct] = __builtin_amdgcn_mfma_f32_16x16x32_bf16(ahA, bh, acc0[ct], 0, 0, 0);
                acc0[ct] = __builtin_amdgcn_mfma_f32_16x16x32_bf16(alA, bh, acc0[ct], 0, 0, 0);
                acc0[ct] = __builtin_amdgcn_mfma_f32_16x16x32_bf16(ahA, bl, acc0[ct], 0, 0, 0);
                acc1[ct] = __builtin_amdgcn_mfma_f32_16x16x32_bf16(ahB, bh, acc1[ct], 0, 0, 0);
                acc1[ct] = __builtin_amdgcn_mfma_f32_16x16x32_bf16(alB, bh, acc1[ct], 0, 0, 0);
                acc1[ct] = __builtin_amdgcn_mfma_f32_16x16x32_bf16(ahB, bl, acc1[ct], 0, 0, 0);
            }
        }
        int rbase = row0 + w * 16 + (lane >> 4) * 4;
        #pragma unroll
        for (int reg = 0; reg < 4; reg++) {
            int grow = rbase + reg;
            if (grow < n) {
                #pragma unroll
                for (int ct = 0; ct < 4; ct++)
                    gout[(size_t)grow * 64 + ct * 16 + rA] = f2b(acc0[ct][reg]);
            }
            int grow2 = grow + 64;
            if (grow2 < n) {
                #pragma unroll
                for (int ct = 0; ct < 4; ct++)
                    gout[(size_t)grow2 * 64 + ct * 16 + rA] = f2b(acc1[ct][reg]);
            }
        }
    } else {
        // ---------------- bin path: 4096 edges
        for (int j = tid; j < NB; j += 256) hist[j] = 0;
        __syncthreads();
        int e0 = (int)blockIdx.x * 4096;
        unsigned long long pk[16]; int bb[16]; int loc[16];
        #pragma unroll
        for (int j = 0; j < 16; j++) {
            int e = e0 + j * 256 + tid;
            if (e < E) {
                int s = src[e];
                int d = dst[e];
                float w = ew[e];
                bb[j] = d >> 8;
                pk[j] = ((unsigned long long)__float_as_uint(w) << 32) |
                        (unsigned)((d & (NPB - 1)) << 17) | (unsigned)s;
                loc[j] = atomicAdd(&hist[bb[j]], 1);
            } else bb[j] = -1;
        }
        __syncthreads();
        for (int j = tid; j < NB; j += 256) hbase[j] = atomicAdd(&bin_cnt[j], hist[j]);
        __syncthreads();
        #pragma unroll
        for (int j = 0; j < 16; j++) {
            if (bb[j] >= 0)
                ebuf[(size_t)bb[j] * CAPE + hbase[bb[j]] + loc[j]] = pk[j];
        }
    }
}

// ==================== pass 2: per-bin LDS-resident count+scan+scatter ====================
__global__ __launch_bounds__(512) void k_csr_build(const unsigned long long* __restrict__ ebuf,
                                                   const int* __restrict__ bin_cnt,
                                                   int2* __restrict__ rowcnt,
                                                   float* __restrict__ dinv,
                                                   unsigned long long* __restrict__ csr,
                                                   int n) {
    __shared__ unsigned long long eL[CAPE];   // 40 KB
    __shared__ unsigned cntL[NPB];
    __shared__ unsigned ewsL[NPB];
    __shared__ unsigned fillL[NPB];
    __shared__ int scanL[512];
    __shared__ int rowL[NPB];
    __shared__ int binbase_s;
    int b = blockIdx.x;
    int tid = threadIdx.x;
    if (tid < NPB) { cntL[tid] = 0; ewsL[tid] = 0; fillL[tid] = 0; }
    scanL[tid] = (tid < b) ? bin_cnt[tid] : 0;
    __syncthreads();
    int m = bin_cnt[b];
    const unsigned long long* eb = ebuf + (size_t)b * CAPE;
    for (int i = tid; i < m; i += 512) {
        unsigned long long pk = eb[i];
        eL[i] = pk;
        int ld = (int)((pk >> 17) & (NPB - 1));
        float w = __uint_as_float((unsigned)(pk >> 32));
        atomicAdd(&cntL[ld], 1u);
        atomicAdd(&ewsL[ld], (unsigned)(w * 16777216.0f));   // 2^24 fixed point
    }
    __syncthreads();
    // bin base = sum of bin_cnt[0..b)
    #pragma unroll
    for (int off = 256; off > 0; off >>= 1) {
        if (tid < off) scanL[tid] += scanL[tid + off];
        __syncthreads();
    }
    if (tid == 0) binbase_s = scanL[0];
    __syncthreads();
    // exclusive prefix over cntL (512-wide, entries >= NPB are zero)
    int v = (tid < NPB) ? (int)cntL[tid] : 0;
    scanL[tid] = v;
    __syncthreads();
    #pragma unroll
    for (int off = 1; off < 512; off <<= 1) {
        int t = (tid >= off) ? scanL[tid - off] : 0;
        __syncthreads();
        scanL[tid] += t;
        __syncthreads();
    }
    if (tid < NPB) {
        int rp = binbase_s + scanL[tid] - v;
        rowL[tid] = rp;
        int node = b * NPB + tid;
        if (node < n) {
            rowcnt[node] = make_int2(rp, v);
            dinv[node] = rsqrtf(1.0f + (float)ewsL[tid] * (1.0f / 16777216.0f));
        }
    }
    __syncthreads();
    // scatter from LDS; csr entry = (src, raw ew)
    for (int i = tid; i < m; i += 512) {
        unsigned long long pk = eL[i];
        int s = (int)(pk & 0x1FFFF);
        int ld = (int)((pk >> 17) & (NPB - 1));
        int pos = rowL[ld] + (int)atomicAdd(&fillL[ld], 1u);
        csr[pos] = (unsigned long long)(unsigned)s | (pk & 0xFFFFFFFF00000000ull);
    }
}

// ==================== layer-2 GEMM (register-direct MFMA, 2 row-tiles/wave) ================
__global__ __launch_bounds__(256) void k_gemm2(const unsigned short* __restrict__ h,
                                               const unsigned short* __restrict__ Wf2,
                                               const float* __restrict__ dinv,
                                               unsigned short* __restrict__ out, int n) {
    int tid = threadIdx.x;
    int row0 = blockIdx.x * 128;
    int w = tid >> 6, lane = tid & 63;
    int rA = lane & 15, g8 = (lane >> 4) * 8;
    int rowa = row0 + w * 16 + rA;
    int rowb = rowa + 64;
    const unsigned short* ha = h + (size_t)min(rowa, n - 1) * 64;
    const unsigned short* hb = h + (size_t)min(rowb, n - 1) * 64;
    f32x4 acc0[4] = {{0.f,0.f,0.f,0.f},{0.f,0.f,0.f,0.f},{0.f,0.f,0.f,0.f},{0.f,0.f,0.f,0.f}};
    f32x4 acc1[4] = {{0.f,0.f,0.f,0.f},{0.f,0.f,0.f,0.f},{0.f,0.f,0.f,0.f},{0.f,0.f,0.f,0.f}};
    #pragma unroll
    for (int kb = 0; kb < 2; kb++) {
        bf16x8 aA = *(const bf16x8*)(ha + kb * 32 + g8);
        bf16x8 aB = *(const bf16x8*)(hb + kb * 32 + g8);
        const unsigned short* wb = Wf2 + (size_t)(kb * 8) * 512 + lane * 8;
        #pragma unroll
        for (int ct = 0; ct < 4; ct++) {
            bf16x8 bh = *(const bf16x8*)(wb + (ct * 2 + 0) * 512);
            bf16x8 bl = *(const bf16x8*)(wb + (ct * 2 + 1) * 512);
            acc0[ct] = __builtin_amdgcn_mfma_f32_16x16x32_bf16(aA, bh, acc0[ct], 0, 0, 0);
            acc0[ct] = __builtin_amdgcn_mfma_f32_16x16x32_bf16(aA, bl, acc0[ct], 0, 0, 0);
            acc1[ct] = __builtin_amdgcn_mfma_f32_16x16x32_bf16(aB, bh, acc1[ct], 0, 0, 0);
            acc1[ct] = __builtin_amdgcn_mfma_f32_16x16x32_bf16(aB, bl, acc1[ct], 0, 0, 0);
        }
    }
    int rbase = row0 + w * 16 + (lane >> 4) * 4;
    #pragma unroll
    for (int reg = 0; reg < 4; reg++) {
        int grow = rbase + reg;
        if (grow < n) {
            float sc = dinv[grow];
            #pragma unroll
            for (int ct = 0; ct < 4; ct++)
                out[(size_t)grow * 64 + ct * 16 + rA] = f2b(acc0[ct][reg] * sc);
        }
        int grow2 = grow + 64;
        if (grow2 < n) {
            float sc = dinv[grow2];
            #pragma unroll
            for (int ct = 0; ct < 4; ct++)
                out[(size_t)grow2 * 64 + ct * 16 + rA] = f2b(acc1[ct][reg] * sc);
        }
    }
}

// -------------------- propagation: one wave per node, 8 edges per VMEM instruction ----------
// DSCALE: msg weight = ew * dinv[src] (gathered, L2-hot), self term * dinv[d] in epilogue.
static __device__ __forceinline__ void acc8(float* a, uint4 r, float wt) {
    a[0] = fmaf(b2f_lo(r.x), wt, a[0]); a[1] = fmaf(b2f_hi(r.x), wt, a[1]);
    a[2] = fmaf(b2f_lo(r.y), wt, a[2]); a[3] = fmaf(b2f_hi(r.y), wt, a[3]);
    a[4] = fmaf(b2f_lo(r.z), wt, a[4]); a[5] = fmaf(b2f_hi(r.z), wt, a[5]);
    a[6] = fmaf(b2f_lo(r.w), wt, a[6]); a[7] = fmaf(b2f_hi(r.w), wt, a[7]);
}

template<bool RELU, bool SPLIT_OUT, bool DSCALE>
__global__ __launch_bounds__(256) void k_prop(const unsigned short* __restrict__ g,
                                              const int2* __restrict__ csr,
                                              const int2* __restrict__ rowcnt,
                                              const float* __restrict__ dinv,
                                              const float* __restrict__ bias0,
                                              const float* __restrict__ bias1,
                                              void* __restrict__ outv, int n) {
    int node = blockIdx.x * 4 + (threadIdx.x >> 6);
    if (node >= n) return;
    int lane = threadIdx.x & 63;
    int q = lane >> 3;          // edge slot 0..7
    int t = lane & 7;           // channel octet: channels 8t..8t+7
    uint4 sr = *(const uint4*)(g + (size_t)node * 64 + t * 8);
    int2 rc = rowcnt[node];
    const int2* ep = csr + rc.x;
    int m = rc.y;
    float a[8] = {};
    if (m > 0 && m <= 16) {
        // short path (~56% of nodes): 16 slots, 2 gathers
        int e1 = q, e2 = q + 8;
        int i1 = min(e1, m - 1), i2 = min(e2, m - 1);
        int2 p1 = ep[i1];
        int2 p2 = ep[i2];
        uint4 r1 = *(const uint4*)(g + (size_t)p1.x * 64 + t * 8);
        uint4 r2 = *(const uint4*)(g + (size_t)p2.x * 64 + t * 8);
        float w1 = (e1 < m) ? __int_as_float(p1.y) : 0.f;
        float w2 = (e2 < m) ? __int_as_float(p2.y) : 0.f;
        if (DSCALE) { w1 *= dinv[p1.x]; w2 *= dinv[p2.x]; }
        acc8(a, r1, w1);
        acc8(a, r2, w2);
    } else {
        for (int e = 0; e < m; e += 32) {
            int e1 = e + q, e2 = e1 + 8, e3 = e1 + 16, e4 = e1 + 24;
            int i1 = min(e1, m - 1), i2 = min(e2, m - 1);
            int i3 = min(e3, m - 1), i4 = min(e4, m - 1);
            int2 p1 = ep[i1];
            int2 p2 = ep[i2];
            int2 p3 = ep[i3];
            int2 p4 = ep[i4];
            uint4 r1 = *(const uint4*)(g + (size_t)p1.x * 64 + t * 8);
            uint4 r2 = *(const uint4*)(g + (size_t)p2.x * 64 + t * 8);
            uint4 r3 = *(const uint4*)(g + (size_t)p3.x * 64 + t * 8);
            uint4 r4 = *(const uint4*)(g + (size_t)p4.x * 64 + t * 8);
            float w1 = (e1 < m) ? __int_as_float(p1.y) : 0.f;
            float w2 = (e2 < m) ? __int_as_float(p2.y) : 0.f;
            float w3 = (e3 < m) ? __int_as_float(p3.y) : 0.f;
            float w4 = (e4 < m) ? __int_as_float(p4.y) : 0.f;
            if (DSCALE) {
                w1 *= dinv[p1.x]; w2 *= dinv[p2.x];
                w3 *= dinv[p3.x]; w4 *= dinv[p4.x];
            }
            acc8(a, r1, w1);
            acc8(a, r2, w2);
            acc8(a, r3, w3);
            acc8(a, r4, w4);
        }
    }
    #pragma unroll
    for (int i = 0; i < 8; i++) {
        a[i] += __shfl_xor(a[i], 8);
        a[i] += __shfl_xor(a[i], 16);
        a[i] += __shfl_xor(a[i], 32);
    }
    if (q != 0) return;
    float di = dinv[node];
    float ss = DSCALE ? di : 1.f;   // self term: dinv[d]*h[d] when DSCALE
    a[0] += ss * b2f_lo(sr.x); a[1] += ss * b2f_hi(sr.x);
    a[2] += ss * b2f_lo(sr.y); a[3] += ss * b2f_hi(sr.y);
    a[4] += ss * b2f_lo(sr.z); a[5] += ss * b2f_hi(sr.z);
    a[6] += ss * b2f_lo(sr.w); a[7] += ss * b2f_hi(sr.w);
    #pragma unroll
    for (int i = 0; i < 8; i++) a[i] *= di;
    if (!SPLIT_OUT) {
        float4 b0 = ld4(bias0 + t * 8);
        float4 b1 = ld4(bias0 + t * 8 + 4);
        a[0] += b0.x; a[1] += b0.y; a[2] += b0.z; a[3] += b0.w;
        a[4] += b1.x; a[5] += b1.y; a[6] += b1.z; a[7] += b1.w;
        if (RELU) {
            #pragma unroll
            for (int i = 0; i < 8; i++) a[i] = fmaxf(a[i], 0.f);
        }
        uint4 u = make_uint4(pk2(a[0], a[1]), pk2(a[2], a[3]),
                             pk2(a[4], a[5]), pk2(a[6], a[7]));
        *(uint4*)((unsigned short*)outv + (size_t)node * 64 + t * 8) = u;
    } else {
        float* out = (float*)outv;
        const float* bp = (t < 4) ? (bias0 + t * 8) : (bias1 + (t - 4) * 8);
        size_t base = (t < 4) ? ((size_t)node * 32 + t * 8)
                              : ((size_t)n * 32 + (size_t)node * 32 + (t - 4) * 8);
        float4 b0 = ld4(bp);
        float4 b1 = ld4(bp + 4);
        float4 v0 = make_float4(a[0] + b0.x, a[1] + b0.y, a[2] + b0.z, a[3] + b0.w);
        float4 v1 = make_float4(a[4] + b1.x, a[5] + b1.y, a[6] + b1.z, a[7] + b1.w);
        *(float4*)&out[base] = v0;
        *(float4*)&out[base + 4] = v1;
    }
}

// -------------------- launch --------------------
extern "C" void kernel_launch(void* const* d_in, const int* in_sizes, int n_in,
                              void* d_out, int out_size, void* d_ws, size_t ws_size,
                              hipStream_t stream) {
    const float* x   = (const float*)d_in[0];
    const int*   ei  = (const int*)d_in[1];   // [2, E]
    const float* ew  = (const float*)d_in[2];
    const float* W1  = (const float*)d_in[3];
    const float* b1  = (const float*)d_in[4];
    const float* Wmu = (const float*)d_in[5];
    const float* bmu = (const float*)d_in[6];
    const float* Wlv = (const float*)d_in[7];
    const float* blv = (const float*)d_in[8];
    float* outp = (float*)d_out;

    const int n = in_sizes[0] / 128;
    const int E = in_sizes[2];
    const int* src = ei;
    const int* dst = ei + E;
    const int NB = (n + NPB - 1) / NPB;            // bins of 256 nodes (391)

    // workspace layout
    size_t o = 0;
    auto alloc = [&](size_t bytes) { void* p = (char*)d_ws + o; o += (bytes + 511) & ~(size_t)511; return p; };
    int*   bin_cnt  = (int*)alloc((size_t)NB * 4);                 // memset 0
    int2*  rowcnt   = (int2*)alloc((size_t)n * 8);
    float* dinv     = (float*)alloc((size_t)n * 4);
    unsigned long long* csr  = (unsigned long long*)alloc((size_t)E * 8);
    unsigned long long* ebuf = (unsigned long long*)alloc((size_t)NB * CAPE * 8);
    unsigned short* g0 = (unsigned short*)alloc((size_t)n * 64 * 2);   // bf16 (raw h from gemm1)
    unsigned short* h  = (unsigned short*)alloc((size_t)n * 64 * 2);   // bf16
    unsigned short* Wf1 = (unsigned short*)alloc(32 * 512 * 2);        // 32 KB
    unsigned short* Wf2 = (unsigned short*)alloc(16 * 512 * 2);        // 16 KB
    unsigned short* g2 = g0;   // gemm2 output reuses g0 (dead after prop1)

    const int gb = (n + 127) / 128;                // gemm blocks (782), 128-row tiles
    const int bb = (E + 4095) / 4096;              // bin blocks (391)

    k_prep<<<2, 256, 0, stream>>>(W1, Wmu, Wlv, Wf1, Wf2);
    hipMemsetAsync(bin_cnt, 0, (size_t)NB * 4, stream);
    k_fused1<<<bb + gb, 256, 0, stream>>>(x, Wf1, g0, src, dst, ew,
                                          bin_cnt, ebuf, n, E, bb, NB);
    k_csr_build<<<NB, 512, 0, stream>>>(ebuf, bin_cnt, rowcnt, dinv, csr, n);
    k_prop<true, false, true><<<(n + 3) / 4, 256, 0, stream>>>(g0, (const int2*)csr, rowcnt, dinv,
                                                               b1, nullptr, h, n);
    k_gemm2<<<(n + 127) / 128, 256, 0, stream>>>(h, Wf2, dinv, g2, n);
    k_prop<false, true, false><<<(n + 3) / 4, 256, 0, stream>>>(g2, (const int2*)csr, rowcnt, dinv,
                                                                bmu, blv, outp, n);
}